// Round 7
// baseline (130.007 us; speedup 1.0000x reference)
//
#include <hip/hip_runtime.h>

#define NT 256

__device__ __forceinline__ int refl(int i, int n) {
    i = (i < 0) ? (-i - 1) : i;
    i = (i >= n) ? (2 * n - 1 - i) : i;
    return i;
}

// Reversed filters: F7[j] = F[7-j], so conv(out c) = sum_j F7[j] * x[2c-6+j]
__device__ __constant__ const float LO7[8] = {
     0.23037781330885523f,  0.7148465705525415f,
     0.6308807679295904f,  -0.02798376941698385f,
    -0.18703481171888114f,  0.030841381835986965f,
     0.032883011666982945f,-0.010597401784997278f };
__device__ __constant__ const float HI7[8] = {
    -0.010597401784997278f,-0.032883011666982945f,
     0.030841381835986965f, 0.18703481171888114f,
    -0.02798376941698385f, -0.6308807679295904f,
     0.7148465705525415f,  -0.23037781330885523f };

// Horizontal lo/hi convolution for one input row, one lane (8 input cols cb..cb+7).
template<bool FAST>
__device__ __forceinline__ void hconv(const float* __restrict__ Ain, int ldin,
                                      int ri, int n, int cb,
                                      float& lo, float& hi)
{
    const int rr = refl(ri, n);
    const float* row = Ain + rr * ldin;
    float v[8];
    if (FAST) {
        const float* p = row + cb;               // cb even -> 8B aligned
        const float2 a0 = *(const float2*)(p);
        const float2 a1 = *(const float2*)(p + 2);
        const float2 a2 = *(const float2*)(p + 4);
        const float2 a3 = *(const float2*)(p + 6);
        v[0] = a0.x; v[1] = a0.y; v[2] = a1.x; v[3] = a1.y;
        v[4] = a2.x; v[5] = a2.y; v[6] = a3.x; v[7] = a3.y;
    } else {
        #pragma unroll
        for (int j = 0; j < 8; ++j) v[j] = row[refl(cb + j, n)];
    }
    float l = 0.f, h = 0.f;
    #pragma unroll
    for (int j = 0; j < 8; ++j) { l += LO7[j] * v[j]; h += HI7[j] * v[j]; }
    lo = l; hi = h;
}

// One wave-tile: 64 output cols x 16 output rows, fully in registers.
// Rolling window W[8]: slot (row & 7) holds that input row's lo/hi.
// r0 multiple of 16 -> 2*r0 % 8 == 0 -> all slot indices static.
template<bool FAST>
__device__ __forceinline__ void do_tile(const float* __restrict__ Ain, int n, int ldin,
                                        int m, int r0, int gc, int cb,
                                        float* __restrict__ oA, int ldA, int oaBase,
                                        float* __restrict__ oH, float* __restrict__ oV,
                                        float* __restrict__ oD, int obBase)
{
    float WL[8], WH[8];
    // prime rows 2r0-6 .. 2r0-1 -> slots 2..7
    #pragma unroll
    for (int i = 0; i < 6; ++i)
        hconv<FAST>(Ain, ldin, 2 * r0 - 6 + i, n, cb, WL[2 + i], WH[2 + i]);

    const bool cok = (gc < m);

    for (int t = 0; t < 4; ++t) {
        #pragma unroll
        for (int u = 0; u < 4; ++u) {
            const int gr = r0 + 4 * t + u;
            // new rows 2gr, 2gr+1 -> slots (2u)&7, (2u+1)&7
            hconv<FAST>(Ain, ldin, 2 * gr,     n, cb, WL[(2 * u) & 7],     WH[(2 * u) & 7]);
            hconv<FAST>(Ain, ldin, 2 * gr + 1, n, cb, WL[(2 * u + 1) & 7], WH[(2 * u + 1) & 7]);
            float A = 0.f, H = 0.f, V = 0.f, D = 0.f;
            #pragma unroll
            for (int j = 0; j < 8; ++j) {
                const int sl = (2 * u + 2 + j) & 7;   // input row 2gr-6+j
                A += LO7[j] * WL[sl];
                H += HI7[j] * WL[sl];
                V += LO7[j] * WH[sl];
                D += HI7[j] * WH[sl];
            }
            if (cok && gr < m) {
                oA[oaBase + gr * ldA] = A;
                const int od = obBase + gr * m;
                oH[od] = H; oV[od] = V; oD[od] = D;
            }
        }
    }
}

// Wave-autonomous fused 2D DWT level: no LDS, no barriers.
// Wave tile = 64 cols x 16 rows; lane owns one output column.
// Tiles ordered y-fastest (b,x,y); XCD-chunked bijective block swizzle.
__global__ __launch_bounds__(NT, 8)
void dwt2_wave(const float* __restrict__ in, int n, int ldin, int inb,
               int m, int nty, int ntx, int ntiles,
               float* __restrict__ oA, int ldA, int Ab,
               float* __restrict__ oH, float* __restrict__ oV,
               float* __restrict__ oD)
{
    const int lane = threadIdx.x & 63;
    const int wv   = threadIdx.x >> 6;

    const int G = gridDim.x;
    const int q = G >> 3, rm = G & 7;
    const int xcd = blockIdx.x & 7, pos = blockIdx.x >> 3;
    const int bp = xcd * q + (xcd < rm ? xcd : rm) + pos;

    const int tile = bp * 4 + wv;
    if (tile >= ntiles) return;

    const int ty = tile % nty;
    const int t2 = tile / nty;
    const int tx = t2 % ntx;
    const int b  = t2 / ntx;

    const int r0 = ty * 16;
    const int c0 = tx * 64;
    const int gc = c0 + lane;
    const int cb = 2 * gc - 6;

    const float* Ain = in + b * inb;
    const int oaBase = b * Ab + gc;
    const int obBase = b * m * m + gc;

    const bool fast = (c0 >= 3) && (2 * c0 + 127 < n);
    if (fast) do_tile<true >(Ain, n, ldin, m, r0, gc, cb, oA, ldA, oaBase, oH, oV, oD, obBase);
    else      do_tile<false>(Ain, n, ldin, m, r0, gc, cb, oA, ldA, oaBase, oH, oV, oD, obBase);
}

extern "C" void kernel_launch(void* const* d_in, const int* in_sizes, int n_in,
                              void* d_out, int out_size, void* d_ws, size_t ws_size,
                              hipStream_t stream) {
    const float* x = (const float*)d_in[0];
    float* out = (float*)d_out;
    float* ws  = (float*)d_ws;

    const int B = 16;
    const int n1 = 1024, m1 = 515;
    const int n2 = 515,  m2 = 261;
    const int n3 = 261,  m3 = 134;

    // padded cA intermediates (rows 16B-aligned, even stride)
    const int ld1 = 516, b1 = m1 * ld1;
    const int ld2 = 264, b2 = m2 * ld2;
    float* a1 = ws;
    float* a2 = ws + (size_t)b1 * B;

    const size_t sz1 = (size_t)B * m1 * m1;
    const size_t sz2 = (size_t)B * m2 * m2;
    const size_t sz3 = (size_t)B * m3 * m3;

    // d_out: a3, lh3, hl3, hh3, lh2, hl2, hh2, lh1, hl1, hh1
    float* a3  = out;
    float* lh3 = a3  + sz3;
    float* hl3 = lh3 + sz3;
    float* hh3 = hl3 + sz3;
    float* lh2 = hh3 + sz3;
    float* hl2 = lh2 + sz2;
    float* hh2 = hl2 + sz2;
    float* lh1 = hh2 + sz2;
    float* hl1 = lh1 + sz1;
    float* hh1 = hl1 + sz1;

    // wave tiles: 64 cols x 16 rows
    const int tx1 = (m1 + 63) / 64, ty1 = (m1 + 15) / 16;   // 9, 33
    const int tx2 = (m2 + 63) / 64, ty2 = (m2 + 15) / 16;   // 5, 17
    const int tx3 = (m3 + 63) / 64, ty3 = (m3 + 15) / 16;   // 3, 9

    const int nt1 = tx1 * ty1 * B;   // 4752
    const int nt2 = tx2 * ty2 * B;   // 1360
    const int nt3 = tx3 * ty3 * B;   // 432

    const int G1 = (nt1 + 3) / 4;    // 1188 blocks (4 waves each)
    const int G2 = (nt2 + 3) / 4;    // 340
    const int G3 = (nt3 + 3) / 4;    // 108

    dim3 blk(NT);
    dwt2_wave<<<dim3(G1), blk, 0, stream>>>(x,  n1, n1, n1 * n1,
                                            m1, ty1, tx1, nt1,
                                            a1, ld1, b1, lh1, hl1, hh1);
    dwt2_wave<<<dim3(G2), blk, 0, stream>>>(a1, n2, ld1, b1,
                                            m2, ty2, tx2, nt2,
                                            a2, ld2, b2, lh2, hl2, hh2);
    dwt2_wave<<<dim3(G3), blk, 0, stream>>>(a2, n3, ld2, b2,
                                            m3, ty3, tx3, nt3,
                                            out, m3, m3 * m3, lh3, hl3, hh3);
}

// Round 8
// 58.352 us; speedup vs baseline: 2.2280x; 2.2280x over previous
//
#include <hip/hip_runtime.h>

#define NT 512

__device__ __forceinline__ int refl(int i, int n) {
    i = (i < 0) ? (-i - 1) : i;
    i = (i >= n) ? (2 * n - 1 - i) : i;
    return i;
}

// round-to-nearest-even bf16 pack of (lo -> low16, hi -> high16)
__device__ __forceinline__ unsigned bpack(float lo, float hi) {
    union { float f; unsigned u; } a, b;
    a.f = lo; b.f = hi;
    const unsigned ua = (a.u + 0x7FFFu + ((a.u >> 16) & 1u)) >> 16;
    const unsigned ub = (b.u + 0x7FFFu + ((b.u >> 16) & 1u)) & 0xFFFF0000u;
    return ua | ub;
}
__device__ __forceinline__ float b_lo(unsigned u) {
    union { unsigned u; float f; } x; x.u = u << 16; return x.f;
}
__device__ __forceinline__ float b_hi(unsigned u) {
    union { unsigned u; float f; } x; x.u = u & 0xFFFF0000u; return x.f;
}

// One fused 2D DWT level, 32x32 output tile per block, NT=512 (4 blocks/CU).
// out[i] = sum_k f[k] * x[refl(2i+1-k)] on both axes.
// Phase A (1 item/thread + 48-thread ragged item, loads batched): horizontal
//   conv -> LDS bf16 (lo,hi) packed, pitch 36 dwords (conflict-free).
// Phase B (exactly 1 item/thread): vertical conv -> 4 subbands.
__global__ __launch_bounds__(NT, 8)
void dwt2_fused(const float* __restrict__ in, int n, int ldin, int inb,
                int m, int nty, int ntx,
                float* __restrict__ oA, int ldA, int Ab,
                float* __restrict__ oH, float* __restrict__ oV,
                float* __restrict__ oD)
{
    constexpr float LOF[8] = {
        -0.010597401784997278f,  0.032883011666982945f,
         0.030841381835986965f, -0.18703481171888114f,
        -0.02798376941698385f,   0.6308807679295904f,
         0.7148465705525415f,    0.23037781330885523f };
    constexpr float HIF[8] = {
        -0.23037781330885523f,   0.7148465705525415f,
        -0.6308807679295904f,   -0.02798376941698385f,
         0.18703481171888114f,   0.030841381835986965f,
        -0.032883011666982945f, -0.010597401784997278f };

    __shared__ unsigned s[70 * 36];   // 10080 B: row t, dword col c = out col c

    // --- bijective XCD-chunked remap, y-fastest tile order (proven R5) ---
    const int G = gridDim.x;
    const int q = G >> 3, rm = G & 7;
    const int xcd = blockIdx.x & 7, pos = blockIdx.x >> 3;
    const int i = xcd * q + (xcd < rm ? xcd : rm) + pos;
    const int ty = i % nty;
    const int t2 = i / nty;
    const int tx = t2 % ntx;
    const int b  = t2 / ntx;

    const int tid = threadIdx.x;
    const int c0 = tx * 32, r0 = ty * 32;
    const float* Ain = in + b * inb;

    const int rb  = 2 * r0 - 6;    // LDS row t <-> input row rb+t (t 0..69)
    const int cw0 = 2 * c0 - 8;    // group g window: cols cw0+8g .. cw0+8g+15

    const bool interior = (rb >= 0) && (rb + 69 < n) && (cw0 >= 0) && (cw0 + 71 < n);

    // ---- Phase A: 560 items = 70 rows x 8 groups (4 out cols each) ----
    // item tid: (tr0,g0); item 512+tid (tid<48): (tr1,g1). Loads batched.
    const int tr0 = tid >> 3, g0 = tid & 7;
    const bool has2 = (tid < 48);
    const int tr1 = 64 + (tid >> 3), g1 = tid & 7;

    float v0[16], v1[16];
    if (interior) {
        const float* p0 = Ain + (rb + tr0) * ldin + (cw0 + 8 * g0);
        const float4 a0 = ((const float4*)p0)[0];
        const float4 a1 = ((const float4*)p0)[1];
        const float4 a2 = ((const float4*)p0)[2];
        const float4 a3 = ((const float4*)p0)[3];
        v0[0]=a0.x; v0[1]=a0.y; v0[2]=a0.z; v0[3]=a0.w;
        v0[4]=a1.x; v0[5]=a1.y; v0[6]=a1.z; v0[7]=a1.w;
        v0[8]=a2.x; v0[9]=a2.y; v0[10]=a2.z; v0[11]=a2.w;
        v0[12]=a3.x; v0[13]=a3.y; v0[14]=a3.z; v0[15]=a3.w;
        if (has2) {
            const float* p1 = Ain + (rb + tr1) * ldin + (cw0 + 8 * g1);
            const float4 b0 = ((const float4*)p1)[0];
            const float4 b1 = ((const float4*)p1)[1];
            const float4 b2 = ((const float4*)p1)[2];
            const float4 b3 = ((const float4*)p1)[3];
            v1[0]=b0.x; v1[1]=b0.y; v1[2]=b0.z; v1[3]=b0.w;
            v1[4]=b1.x; v1[5]=b1.y; v1[6]=b1.z; v1[7]=b1.w;
            v1[8]=b2.x; v1[9]=b2.y; v1[10]=b2.z; v1[11]=b2.w;
            v1[12]=b3.x; v1[13]=b3.y; v1[14]=b3.z; v1[15]=b3.w;
        }
    } else {
        const float* row0 = Ain + refl(rb + tr0, n) * ldin;
        const int cb0 = cw0 + 8 * g0;
        #pragma unroll
        for (int u = 0; u < 16; ++u) v0[u] = row0[refl(cb0 + u, n)];
        if (has2) {
            const float* row1 = Ain + refl(rb + tr1, n) * ldin;
            const int cb1 = cw0 + 8 * g1;
            #pragma unroll
            for (int u = 0; u < 16; ++u) v1[u] = row1[refl(cb1 + u, n)];
        }
    }

    {
        unsigned w[4];
        #pragma unroll
        for (int d = 0; d < 4; ++d) {
            float lo = 0.f, hi = 0.f;
            #pragma unroll
            for (int k = 0; k < 8; ++k) {
                const float x = v0[2 * d + 9 - k];
                lo += LOF[k] * x;
                hi += HIF[k] * x;
            }
            w[d] = bpack(lo, hi);
        }
        *(uint4*)&s[tr0 * 36 + 4 * g0] = make_uint4(w[0], w[1], w[2], w[3]);
    }
    if (has2) {
        unsigned w[4];
        #pragma unroll
        for (int d = 0; d < 4; ++d) {
            float lo = 0.f, hi = 0.f;
            #pragma unroll
            for (int k = 0; k < 8; ++k) {
                const float x = v1[2 * d + 9 - k];
                lo += LOF[k] * x;
                hi += HIF[k] * x;
            }
            w[d] = bpack(lo, hi);
        }
        *(uint4*)&s[tr1 * 36 + 4 * g1] = make_uint4(w[0], w[1], w[2], w[3]);
    }
    __syncthreads();

    // ---- Phase B: exactly 1 item/thread: col c, row-pair pr ----
    const int c = tid & 31, pr = tid >> 5;   // pr 0..15
    float lov[10], hiv[10];
    #pragma unroll
    for (int j = 0; j < 10; ++j) {
        const unsigned u = s[(4 * pr + j) * 36 + c];
        lov[j] = b_lo(u); hiv[j] = b_hi(u);
    }
    float A0 = 0.f, H0 = 0.f, V0 = 0.f, D0 = 0.f;
    float A1 = 0.f, H1 = 0.f, V1 = 0.f, D1 = 0.f;
    #pragma unroll
    for (int k = 0; k < 8; ++k) {
        const float l0 = lov[7 - k], h0 = hiv[7 - k];
        const float l1 = lov[9 - k], h1 = hiv[9 - k];
        A0 += LOF[k] * l0;  H0 += HIF[k] * l0;
        V0 += LOF[k] * h0;  D0 += HIF[k] * h0;
        A1 += LOF[k] * l1;  H1 += HIF[k] * l1;
        V1 += LOF[k] * h1;  D1 += HIF[k] * h1;
    }
    const int gr = r0 + 2 * pr, gc = c0 + c;
    if (gc < m) {
        const int ob = b * (m * m);
        const int od = ob + gr * m + gc;
        if (gr < m) {
            oA[b * Ab + gr * ldA + gc] = A0;
            oH[od] = H0; oV[od] = V0; oD[od] = D0;
        }
        if (gr + 1 < m) {
            oA[b * Ab + (gr + 1) * ldA + gc] = A1;
            oH[od + m] = H1; oV[od + m] = V1; oD[od + m] = D1;
        }
    }
}

extern "C" void kernel_launch(void* const* d_in, const int* in_sizes, int n_in,
                              void* d_out, int out_size, void* d_ws, size_t ws_size,
                              hipStream_t stream) {
    const float* x = (const float*)d_in[0];
    float* out = (float*)d_out;
    float* ws  = (float*)d_ws;

    const int B = 16;
    const int n1 = 1024, m1 = 515;
    const int n2 = 515,  m2 = 261;
    const int n3 = 261,  m3 = 134;

    // padded cA intermediates (rows 16B-aligned)
    const int ld1 = 516, b1 = m1 * ld1;
    const int ld2 = 264, b2 = m2 * ld2;
    float* a1 = ws;
    float* a2 = ws + (size_t)b1 * B;

    const size_t sz1 = (size_t)B * m1 * m1;
    const size_t sz2 = (size_t)B * m2 * m2;
    const size_t sz3 = (size_t)B * m3 * m3;

    // d_out: a3, lh3, hl3, hh3, lh2, hl2, hh2, lh1, hl1, hh1
    float* a3  = out;
    float* lh3 = a3  + sz3;
    float* hl3 = lh3 + sz3;
    float* hh3 = hl3 + sz3;
    float* lh2 = hh3 + sz3;
    float* hl2 = lh2 + sz2;
    float* hh2 = hl2 + sz2;
    float* lh1 = hh2 + sz2;
    float* hl1 = lh1 + sz1;
    float* hh1 = hl1 + sz1;

    const int t1 = (m1 + 31) / 32;   // 17
    const int t2_ = (m2 + 31) / 32;  // 9
    const int t3 = (m3 + 31) / 32;   // 5

    dim3 blk(NT);
    dim3 g1(t1 * t1 * B, 1, 1);      // 4624
    dim3 g2(t2_ * t2_ * B, 1, 1);    // 1296
    dim3 g3(t3 * t3 * B, 1, 1);      // 400

    dwt2_fused<<<g1, blk, 0, stream>>>(x,  n1, n1, n1 * n1,
                                       m1, t1, t1, a1, ld1, b1, lh1, hl1, hh1);
    dwt2_fused<<<g2, blk, 0, stream>>>(a1, n2, ld1, b1,
                                       m2, t2_, t2_, a2, ld2, b2, lh2, hl2, hh2);
    dwt2_fused<<<g3, blk, 0, stream>>>(a2, n3, ld2, b2,
                                       m3, t3, t3, out, m3, m3 * m3, lh3, hl3, hh3);
}